// Round 8
// baseline (266.617 us; speedup 1.0000x reference)
//
#include <hip/hip_runtime.h>

typedef unsigned short u16;
typedef unsigned char u8;
typedef unsigned int u32;
typedef __attribute__((ext_vector_type(4))) float f32x4;
typedef __attribute__((ext_vector_type(16))) float f32x16;
typedef __attribute__((ext_vector_type(8))) __bf16 bf16x8;
typedef __attribute__((ext_vector_type(4))) int i32x4;
typedef __attribute__((ext_vector_type(16))) int i32x16;

__device__ __forceinline__ u16 f2bf(float f) {
  u32 u = __float_as_uint(f);
  u32 r = (u + 0x7fffu + ((u >> 16) & 1u)) >> 16;
  return (u16)r;
}

__device__ __forceinline__ float load_thr(const int* p) {
  int iv = *p;
  float fv = __int_as_float(iv);
  if (fv >= 1.0f && fv <= 1.0e6f) return fv;
  return (float)iv;
}

__device__ __forceinline__ void gload_lds16(const void* g, void* l) {
  __builtin_amdgcn_global_load_lds(
      (const __attribute__((address_space(1))) void*)g,
      (__attribute__((address_space(3))) void*)l, 16, 0, 0);
}

// ---------------- colmax over rows of x ----------------
__global__ void k_init_cm(u32* cm, int K) {
  int i = blockIdx.x * 256 + threadIdx.x;
  if (i < K) cm[i] = 0u;
}

__global__ __launch_bounds__(256) void k_colmax(const float* __restrict__ x,
                                                u32* __restrict__ cm, int M,
                                                int K, int rpb) {
  int c4 = blockIdx.x * 256 + threadIdx.x;
  int r0 = blockIdx.y * rpb;
  int r1 = r0 + rpb;
  if (r1 > M) r1 = M;
  f32x4 mx = {0.f, 0.f, 0.f, 0.f};
  for (int r = r0; r < r1; ++r) {
    f32x4 v = *(const f32x4*)&x[(size_t)r * K + (size_t)c4 * 4];
#pragma unroll
    for (int i = 0; i < 4; ++i) mx[i] = fmaxf(mx[i], fabsf(v[i]));
  }
#pragma unroll
  for (int i = 0; i < 4; ++i)
    atomicMax(&cm[c4 * 4 + i], __float_as_uint(mx[i]));
}

// ---------------- ordered outlier-column compaction (1 wave) -------------
__global__ void k_ocols(const u32* __restrict__ cm, const int* __restrict__ thr_i,
                        int K, int* __restrict__ meta) {
  int lane = threadIdx.x;  // 64 threads
  float thr = load_thr(thr_i);
  const float* cmf = (const float*)cm;
  int per = K >> 6;
  int base = lane * per;
  int c = 0;
  for (int i = 0; i < per; ++i) c += (cmf[base + i] > thr) ? 1 : 0;
  int inc = c;
  for (int off = 1; off < 64; off <<= 1) {
    int t = __shfl_up(inc, off);
    if (lane >= off) inc += t;
  }
  int excl = inc - c;
  int total = __shfl(inc, 63);
  if (lane == 0) meta[0] = total < 64 ? total : 64;
  int idx = excl;
  for (int i = 0; i < per; ++i) {
    if (cmf[base + i] > thr) {
      if (idx < 64) meta[1 + idx] = base + i;
      idx++;
    }
  }
  for (int j = total + lane; j < 64; j += 64) meta[1 + j] = -1;
}

// ---------------- row-wise int8 quant (TILED output) + outlier gather ----
// qdst int8 tiled [rows/32][K/32][32][32]; sdst f32/row; odst bf16 [rows,64].
__global__ __launch_bounds__(256) void k_quant8(
    const float* __restrict__ src, const u32* __restrict__ cm,
    const int* __restrict__ thr_i, const int* __restrict__ meta,
    char* __restrict__ qdst, float* __restrict__ sdst, u16* __restrict__ odst,
    int K, int zero_outlier) {
  int row = blockIdx.x;
  int tid = threadIdx.x;
  float thr = load_thr(thr_i);
  const float* sr = src + (size_t)row * K;
  const float* cmf = (const float*)cm;

  float v[16];
  u32 omask = 0;
  float lmax = 0.f;
#pragma unroll
  for (int j = 0; j < 4; ++j) {
    int c4 = j * 256 + tid;
    f32x4 val = *(const f32x4*)&sr[c4 * 4];
    f32x4 cv = *(const f32x4*)&cmf[c4 * 4];
#pragma unroll
    for (int i = 0; i < 4; ++i) {
      float xv = val[i];
      v[j * 4 + i] = xv;
      bool is_out = cv[i] > thr;
      if (is_out) omask |= 1u << (j * 4 + i);
      if (!is_out || !zero_outlier) lmax = fmaxf(lmax, fabsf(xv));
    }
  }
  float m = lmax;
#pragma unroll
  for (int off = 32; off >= 1; off >>= 1) m = fmaxf(m, __shfl_down(m, off));
  __shared__ float red[4];
  int lane = tid & 63, wv = tid >> 6;
  if (lane == 0) red[wv] = m;
  __syncthreads();
  float rm = fmaxf(fmaxf(red[0], red[1]), fmaxf(red[2], red[3]));
  float s = fmaxf(rm / 127.0f, 1e-8f);

  // tiled write: u32 index = ((row>>5)*(K>>5) + (c4>>3))*256 + (row&31)*8 + (c4&7)
  u32* qt = (u32*)qdst;
  size_t rowpart = (size_t)(row >> 5) * (K >> 5) * 256 + (size_t)(row & 31) * 8;
#pragma unroll
  for (int j = 0; j < 4; ++j) {
    int c4 = j * 256 + tid;
    u32 pk = 0;
#pragma unroll
    for (int i = 0; i < 4; ++i) {
      float xv = v[j * 4 + i];
      int iq;
      if (zero_outlier && (omask & (1u << (j * 4 + i)))) {
        iq = 0;
      } else {
        float q = rintf(xv / s);  // round-half-even, matches jnp.round
        q = fminf(fmaxf(q, -127.f), 127.f);
        iq = (int)q;
      }
      pk |= ((u32)(u8)(char)iq) << (8 * i);
    }
    qt[rowpart + (size_t)(c4 >> 3) * 256 + (c4 & 7)] = pk;
  }
  if (tid == 0) sdst[row] = s;
  if (tid < 64) {
    int n_out = meta[0];
    int oc = meta[1 + tid];
    u16 ov = 0;
    if (tid < n_out && oc >= 0) ov = f2bf(sr[oc]);
    odst[(size_t)row * 64 + tid] = ov;
  }
}

// ---------------- i8 GEMM: A direct-from-L2 (tiled), B via LDS -----------
// out = sx[m]*sw[n]*(qx @ qw^T) + x_o @ w_o^T + bias
// Block 256x256, 8 waves 4Mx2N (per-wave 64x128), BK=128.
// qx/qw tiled 1KB blocks; A frags loaded straight from global (one 1KB
// block per wave64 load, fully coalesced, L2-resident via XCD swizzle);
// B staged linearly into 32KB dbuf LDS, frag reads conflict-free by layout.
__global__ __launch_bounds__(512, 2) void k_gemm_i8(
    const char* __restrict__ qx, const char* __restrict__ qw,
    const float* __restrict__ sx, const float* __restrict__ sw,
    const float* __restrict__ bias, const char* __restrict__ xo,
    const char* __restrict__ wo, float* __restrict__ out, int M, int N,
    int K) {
  extern __shared__ char lds_raw[];  // 64 KB: Bbuf[2][32768]
  int tid = threadIdx.x;
  int lane = tid & 63, wave = tid >> 6;
  int wm = wave >> 1, wn = wave & 1;  // 4M x 2N wave grid

  int nwg = gridDim.x, bid = blockIdx.x;
  int swzb = (bid & 7) * (nwg >> 3) + (bid >> 3);
  int nbn = N >> 8;
  int bm = swzb / nbn, bn = swzb % nbn;
  int r0 = bm << 8, c0 = bn << 8;
  int K32 = K >> 5;
  int lbyte = (lane & 31) * 32 + (lane >> 5) * 16;  // intra-1KB-block offset

  // ---- B staging precompute: 4 granules/thread, LDS linear ----
  size_t bpart[4];
  int bg[4];
#pragma unroll
  for (int i = 0; i < 4; ++i) {
    int g = tid + i * 512;          // granule 0..2047
    int b = g >> 6;                 // 1KB block 0..31
    int nb = b >> 2, kb = b & 3;    // n-block 0..7, k-block 0..3
    bpart[i] = ((size_t)((c0 >> 5) + nb) * K32 + kb) * 1024 + (g & 63) * 16;
    bg[i] = g;
  }
#define STAGE_B(bufp, kt)                                                     \
  {                                                                           \
    _Pragma("unroll") for (int i = 0; i < 4; ++i)                             \
        gload_lds16(qw + bpart[i] + ((size_t)((kt) >> 5) << 10),              \
                    (bufp) + bg[i] * 16);                                     \
  }

  // ---- A direct loads: 8 frags (q x ks) per tile ----
  const char* abase0 = qx + ((size_t)((r0 >> 5) + wm * 2) * K32 << 10) + lbyte;
  const char* abase1 = abase0 + ((size_t)K32 << 10);
#define LOAD_A(ar, kt)                                                        \
  {                                                                           \
    _Pragma("unroll") for (int ks = 0; ks < 4; ++ks) {                        \
      ar[ks] = *(const i32x4*)(abase0 + ((size_t)(((kt) >> 5) + ks) << 10));  \
      ar[4 + ks] =                                                            \
          *(const i32x4*)(abase1 + ((size_t)(((kt) >> 5) + ks) << 10));       \
    }                                                                         \
  }

  // ---- B frag read from LDS (tiled layout -> naturally conflict-free) ----
#define BFR(dst, bufp, nf, ks)                                                \
  dst = *(const i32x4*)((bufp) + ((((wn * 4 + (nf)) * 4 + (ks)) << 10)) +     \
                        lbyte);

#define MFI(q, nf, av, bv)                                                    \
  asm volatile("v_mfma_i32_32x32x32_i8 %0, %1, %2, %0"                        \
               : "+v"(acc[q][nf])                                             \
               : "v"(av), "v"(bv))

  // MFMA cluster for nf-pair p (16 MFMA), chains interleaved across 4 accs
#define CLUST(ac, p)                                                          \
  {                                                                           \
    __builtin_amdgcn_s_setprio(1);                                            \
    _Pragma("unroll") for (int ks = 0; ks < 4; ++ks) {                        \
      MFI(0, 2 * (p), ac[ks], Bf[ks]);                                        \
      MFI(0, 2 * (p) + 1, ac[ks], Bf[4 + ks]);                                \
      MFI(1, 2 * (p), ac[4 + ks], Bf[ks]);                                    \
      MFI(1, 2 * (p) + 1, ac[4 + ks], Bf[4 + ks]);                            \
    }                                                                         \
    __builtin_amdgcn_s_setprio(0);                                            \
  }

  // one K-tile: compute from (bufc, ac), stage next into (bufn, an)
#define TILE(bufc, bufn, ac, an, ktn)                                         \
  {                                                                           \
    STAGE_B(bufn, ktn);                                                       \
    LOAD_A(an, ktn);                                                          \
    __builtin_amdgcn_sched_barrier(0);                                        \
    i32x4 Bf[8];                                                              \
    BFR(Bf[0], bufc, 0, 0); BFR(Bf[1], bufc, 0, 1);                           \
    BFR(Bf[2], bufc, 0, 2); BFR(Bf[3], bufc, 0, 3);                           \
    BFR(Bf[4], bufc, 1, 0); BFR(Bf[5], bufc, 1, 1);                           \
    BFR(Bf[6], bufc, 1, 2); BFR(Bf[7], bufc, 1, 3);                           \
    CLUST(ac, 0);                                                             \
    BFR(Bf[0], bufc, 2, 0); BFR(Bf[1], bufc, 2, 1);                           \
    BFR(Bf[2], bufc, 2, 2); BFR(Bf[3], bufc, 2, 3);                           \
    BFR(Bf[4], bufc, 3, 0); BFR(Bf[5], bufc, 3, 1);                           \
    BFR(Bf[6], bufc, 3, 2); BFR(Bf[7], bufc, 3, 3);                           \
    CLUST(ac, 1);                                                             \
    asm volatile("s_waitcnt vmcnt(0)" ::: "memory");                          \
    __builtin_amdgcn_s_barrier();                                             \
  }

  char* buf0 = lds_raw;
  char* buf1 = lds_raw + 32768;
  i32x16 acc[2][4] = {};
  i32x4 aA[8], aB[8];

  // prologue: tile 0 into buf0/aA
  STAGE_B(buf0, 0);
  LOAD_A(aA, 0);
  asm volatile("s_waitcnt vmcnt(0)" ::: "memory");
  __builtin_amdgcn_s_barrier();

  int nit = K / 256;  // 2 tiles per iter
  for (int it = 0; it < nit; ++it) {
    int kt1 = it * 256 + 128;
    int kt2 = it * 256 + 256;
    kt2 = (kt2 < K) ? kt2 : 0;  // dummy stage on final iter
    TILE(buf0, buf1, aA, aB, kt1);
    TILE(buf1, buf0, aB, aA, kt2);
  }

  // --------- epilogue: stage outlier panels (256 rows x 128 B each) ------
#pragma unroll
  for (int i = 0; i < 4; ++i) {
    int g = tid + i * 512;
    int rw = g >> 3;
    int cb = ((g & 7) ^ (rw & 7)) << 4;
    gload_lds16(xo + (size_t)(r0 + rw) * 128 + cb, lds_raw + g * 16);
    gload_lds16(wo + (size_t)(c0 + rw) * 128 + cb, lds_raw + 32768 + g * 16);
  }

  // scale conversion: C/D 32x32: col=lane&31, row=(reg&3)+8*(reg>>2)+4*(lane>>5)
  f32x16 facc[2][4];
  float swv[4], bv[4];
#pragma unroll
  for (int nf = 0; nf < 4; ++nf) {
    swv[nf] = sw[c0 + wn * 128 + nf * 32 + (lane & 31)];
    bv[nf] = bias[c0 + wn * 128 + nf * 32 + (lane & 31)];
  }
#pragma unroll
  for (int q = 0; q < 2; ++q) {
    int gmb = r0 + wm * 64 + q * 32 + 4 * (lane >> 5);
    f32x4 s4a = *(const f32x4*)&sx[gmb];
    f32x4 s4b = *(const f32x4*)&sx[gmb + 8];
    f32x4 s4c = *(const f32x4*)&sx[gmb + 16];
    f32x4 s4d = *(const f32x4*)&sx[gmb + 24];
#pragma unroll
    for (int reg = 0; reg < 16; ++reg) {
      float sxv = (reg < 4) ? s4a[reg & 3]
                : (reg < 8) ? s4b[reg & 3]
                : (reg < 12) ? s4c[reg & 3] : s4d[reg & 3];
#pragma unroll
      for (int nf = 0; nf < 4; ++nf)
        facc[q][nf][reg] = (float)acc[q][nf][reg] * sxv * swv[nf];
    }
  }

  asm volatile("s_waitcnt vmcnt(0)" ::: "memory");
  __builtin_amdgcn_s_barrier();

  // outlier bf16 GEMM over K=64 into the scaled accumulators
#pragma unroll
  for (int ks = 0; ks < 4; ++ks) {
    bf16x8 ob[4];
#pragma unroll
    for (int nf = 0; nf < 4; ++nf) {
      int rn = wn * 128 + nf * 32 + (lane & 31);
      ob[nf] = *(const bf16x8*)(lds_raw + 32768 + rn * 128 +
                                (((ks * 2 + (lane >> 5)) ^ (rn & 7)) << 4));
    }
#pragma unroll
    for (int q = 0; q < 2; ++q) {
      int rl = wm * 64 + q * 32 + (lane & 31);
      bf16x8 oa = *(const bf16x8*)(lds_raw + rl * 128 +
                                   (((ks * 2 + (lane >> 5)) ^ (rl & 7)) << 4));
#pragma unroll
      for (int nf = 0; nf < 4; ++nf)
        facc[q][nf] = __builtin_amdgcn_mfma_f32_32x32x16_bf16(
            oa, ob[nf], facc[q][nf], 0, 0, 0);
    }
  }

#pragma unroll
  for (int q = 0; q < 2; ++q) {
#pragma unroll
    for (int reg = 0; reg < 16; ++reg) {
      int gm = r0 + wm * 64 + q * 32 + (reg & 3) + 8 * (reg >> 2) +
               4 * (lane >> 5);
      float* orow = out + (size_t)gm * N + c0 + wn * 128 + (lane & 31);
#pragma unroll
      for (int nf = 0; nf < 4; ++nf)
        orow[nf * 32] = facc[q][nf][reg] + bv[nf];
    }
  }
}

extern "C" void kernel_launch(void* const* d_in, const int* in_sizes, int n_in,
                              void* d_out, int out_size, void* d_ws,
                              size_t ws_size, hipStream_t stream) {
  const float* x = (const float*)d_in[0];
  const float* W = (const float*)d_in[1];
  const float* bias = (const float*)d_in[2];
  const int* thr = (const int*)d_in[3];
  float* out = (float*)d_out;

  int N = in_sizes[2];
  int K = in_sizes[1] / N;
  int M = in_sizes[0] / K;

  char* ws = (char*)d_ws;
  u32* cm = (u32*)ws;                       // K u32 (16 KB)
  int* meta = (int*)(ws + 16384);           // 65 ints
  float* sx = (float*)(ws + 32768);         // M f32
  float* sw = (float*)(ws + 32768 + (size_t)M * 4);          // N f32
  char* xo = ws + 32768 + (size_t)(M + N) * 4;               // M*64 bf16
  char* wo = xo + (size_t)M * 128;                           // N*64 bf16
  char* qx = wo + (size_t)N * 128;                           // M*K int8 tiled
  char* qw = qx + (size_t)M * K;                             // N*K int8 tiled

  k_init_cm<<<dim3((K + 255) / 256), dim3(256), 0, stream>>>(cm, K);

  {
    int gx = K / 1024;
    int gy = 128;
    int rpb = (M + gy - 1) / gy;
    k_colmax<<<dim3(gx, gy), dim3(256), 0, stream>>>(x, cm, M, K, rpb);
  }

  k_ocols<<<dim3(1), dim3(64), 0, stream>>>(cm, thr, K, meta);

  k_quant8<<<dim3(M), dim3(256), 0, stream>>>(x, cm, thr, meta, qx, sx,
                                              (u16*)xo, K, 1);
  k_quant8<<<dim3(N), dim3(256), 0, stream>>>(W, cm, thr, meta, qw, sw,
                                              (u16*)wo, K, 0);

  (void)hipFuncSetAttribute((const void*)k_gemm_i8,
                            hipFuncAttributeMaxDynamicSharedMemorySize,
                            65536);
  int nwg = (M / 256) * (N / 256);
  k_gemm_i8<<<dim3(nwg), dim3(512), 65536, stream>>>(qx, qw, sx, sw, bias,
                                                     xo, wo, out, M, N, K);
}